// Round 1
// baseline (61.061 us; speedup 1.0000x reference)
//
#include <hip/hip_runtime.h>
#include <math.h>

#define BB 256
#define FF 39
#define EE 16
#define II 741
#define BN_EPS 1e-5f

// ws layout (floats): Si[B*F], Qi[B*F], Sj[B*F], Qj[B*F], A[I], D[I]
// NROW = B*F = 9984 -> total 4*9984 + 2*741 = 41418 floats = ~166 KB

__global__ void rowsum_kernel(const float* __restrict__ xi,
                              const float* __restrict__ xj,
                              float* __restrict__ ws) {
    const int NROW = BB * FF;  // 9984
    int t = blockIdx.x * blockDim.x + threadIdx.x;
    if (t >= 2 * NROW) return;
    int tensor = (t >= NROW) ? 1 : 0;
    int row = tensor ? (t - NROW) : t;
    const float* src = (tensor ? xj : xi) + row * EE;
    float s = 0.f, q = 0.f;
#pragma unroll
    for (int k = 0; k < 4; ++k) {
        float4 v = reinterpret_cast<const float4*>(src)[k];
        s += v.x + v.y + v.z + v.w;
        q += v.x * v.x + v.y * v.y + v.z * v.z + v.w * v.w;
    }
    float* base = ws + (tensor ? 2 * NROW : 0);
    base[row] = s;           // S
    base[NROW + row] = q;    // Q
}

__global__ void stats_kernel(const float* __restrict__ gamma,
                             const float* __restrict__ beta,
                             float* __restrict__ ws) {
    int i = blockIdx.x * blockDim.x + threadIdx.x;
    if (i >= II) return;
    // invert strict-lower-tri row-major index: i = r*(r-1)/2 + c, c < r
    int r = (int)((1.0f + sqrtf(8.0f * (float)i + 1.0f)) * 0.5f);
    while (r * (r - 1) / 2 > i) --r;
    while ((r + 1) * r / 2 <= i) ++r;
    int c = i - r * (r - 1) / 2;

    const int NROW = BB * FF;
    const float* Si = ws;
    const float* Qi = ws + NROW;
    const float* Sj = ws + 2 * NROW;
    const float* Qj = ws + 3 * NROW;
    float sumS = 0.f, sumQ = 0.f;
    for (int b = 0; b < BB; ++b) {
        sumS += Sj[b * FF + r] * Si[b * FF + c];
        sumQ += Qj[b * FF + r] * Qi[b * FF + c];
    }
    const float invN = 1.0f / (float)(BB * EE * EE);  // 1/65536
    float mean = sumS * invN;
    float ex2 = sumQ * invN;
    float var = ex2 - mean * mean;
    float inv_std = 1.0f / sqrtf(var + BN_EPS);
    float a = gamma[i] * inv_std;
    float d = beta[i] - mean * a;
    float* A = ws + 4 * NROW;
    float* D = A + II;
    A[i] = a;
    D[i] = d;
}

// out[b,i,e1,e2] = ((xj[b,r,e1]*xi[b,c,e2]) * a[i] + d[i]) * W[e1,e2]
// Block: 256 threads = 4 waves; each wave handles 4 consecutive channels,
// block handles 16 channels for one batch b. Wave writes contiguous 1 KB
// per channel (64 lanes x float4).
__global__ __launch_bounds__(256) void
cross_bn_kernel(const float* __restrict__ xi,
                const float* __restrict__ xj,
                const float* __restrict__ W,
                const float* __restrict__ ws,
                float* __restrict__ out) {
    const int NROW = BB * FF;
    const float* A = ws + 4 * NROW;
    const float* D = A + II;

    int b = blockIdx.y;
    int t = threadIdx.x;
    int l = t & 63;        // lane in wave
    int e1 = l >> 2;       // 0..15
    int e2q = l & 3;       // float4 index along e2
    int csub = t >> 6;     // wave id 0..3

    float4 w4 = reinterpret_cast<const float4*>(W)[e1 * 4 + e2q];

    const float* xib = xi + b * FF * EE;
    const float* xjb = xj + b * FF * EE;
    float* outb = out + (size_t)b * II * EE * EE;

    int ibase = blockIdx.x * 16 + csub * 4;
#pragma unroll
    for (int k = 0; k < 4; ++k) {
        int i = ibase + k;
        if (i >= II) break;  // wave-uniform
        int r = (int)((1.0f + sqrtf(8.0f * (float)i + 1.0f)) * 0.5f);
        while (r * (r - 1) / 2 > i) --r;
        while ((r + 1) * r / 2 <= i) ++r;
        int c = i - r * (r - 1) / 2;

        float xjs = xjb[r * EE + e1];
        float4 xi4 = reinterpret_cast<const float4*>(xib + c * EE)[e2q];
        float a = A[i];
        float d = D[i];
        float4 o;
        o.x = (xjs * xi4.x * a + d) * w4.x;
        o.y = (xjs * xi4.y * a + d) * w4.y;
        o.z = (xjs * xi4.z * a + d) * w4.z;
        o.w = (xjs * xi4.w * a + d) * w4.w;
        reinterpret_cast<float4*>(outb + (size_t)i * (EE * EE))[l] = o;
    }
}

extern "C" void kernel_launch(void* const* d_in, const int* in_sizes, int n_in,
                              void* d_out, int out_size, void* d_ws, size_t ws_size,
                              hipStream_t stream) {
    const float* xi = (const float*)d_in[0];
    const float* xj = (const float*)d_in[1];
    const float* W = (const float*)d_in[2];
    const float* gamma = (const float*)d_in[3];
    const float* beta = (const float*)d_in[4];
    float* out = (float*)d_out;
    float* ws = (float*)d_ws;

    const int NROW = BB * FF;
    rowsum_kernel<<<dim3((2 * NROW + 255) / 256), 256, 0, stream>>>(xi, xj, ws);
    stats_kernel<<<dim3((II + 255) / 256), 256, 0, stream>>>(gamma, beta, ws);
    cross_bn_kernel<<<dim3((II + 15) / 16, BB), 256, 0, stream>>>(xi, xj, W, ws, out);
}

// Round 3
// 51.508 us; speedup vs baseline: 1.1855x; 1.1855x over previous
//
#include <hip/hip_runtime.h>
#include <math.h>

#define BB 256
#define FF 39
#define EE 16
#define II 741
#define BN_EPS 1e-5f

typedef float vfloat4 __attribute__((ext_vector_type(4)));

// ws layout (floats): Si[B*F], Qi[B*F], Sj[B*F], Qj[B*F], T[I]*4 (a,d,r*16,c*16)
// NROW = B*F = 9984 -> 4*9984 + 4*741 floats = ~172 KB

__global__ void rowsum_kernel(const float* __restrict__ xi,
                              const float* __restrict__ xj,
                              float* __restrict__ ws) {
    const int NROW = BB * FF;  // 9984
    int t = blockIdx.x * blockDim.x + threadIdx.x;
    if (t >= 2 * NROW) return;
    int tensor = (t >= NROW) ? 1 : 0;
    int row = tensor ? (t - NROW) : t;
    const float* src = (tensor ? xj : xi) + row * EE;
    float s = 0.f, q = 0.f;
#pragma unroll
    for (int k = 0; k < 4; ++k) {
        vfloat4 v = reinterpret_cast<const vfloat4*>(src)[k];
        s += v.x + v.y + v.z + v.w;
        q += v.x * v.x + v.y * v.y + v.z * v.z + v.w * v.w;
    }
    float* base = ws + (tensor ? 2 * NROW : 0);
    base[row] = s;           // S
    base[NROW + row] = q;    // Q
}

// One wave per channel: lanes split batch dim, butterfly-reduce, lane 0
// writes packed per-channel table entry T[i] = (a, d, r*16, c*16).
__global__ __launch_bounds__(256) void
stats_kernel(const float* __restrict__ gamma,
             const float* __restrict__ beta,
             float* __restrict__ ws) {
    int wid = (blockIdx.x * blockDim.x + threadIdx.x) >> 6;  // global wave = channel
    int lane = threadIdx.x & 63;
    if (wid >= II) return;
    int i = wid;
    // invert strict-lower-tri row-major index: i = r*(r-1)/2 + c, c < r
    int r = (int)((1.0f + sqrtf(8.0f * (float)i + 1.0f)) * 0.5f);
    while (r * (r - 1) / 2 > i) --r;
    while ((r + 1) * r / 2 <= i) ++r;
    int c = i - r * (r - 1) / 2;

    const int NROW = BB * FF;
    const float* Si = ws;
    const float* Qi = ws + NROW;
    const float* Sj = ws + 2 * NROW;
    const float* Qj = ws + 3 * NROW;

    float sumS = 0.f, sumQ = 0.f;
#pragma unroll
    for (int b = lane; b < BB; b += 64) {
        sumS += Sj[b * FF + r] * Si[b * FF + c];
        sumQ += Qj[b * FF + r] * Qi[b * FF + c];
    }
#pragma unroll
    for (int off = 32; off > 0; off >>= 1) {
        sumS += __shfl_xor(sumS, off);
        sumQ += __shfl_xor(sumQ, off);
    }
    if (lane == 0) {
        const float invN = 1.0f / (float)(BB * EE * EE);  // 1/65536
        float mean = sumS * invN;
        float ex2 = sumQ * invN;
        float var = ex2 - mean * mean;
        float inv_std = 1.0f / sqrtf(var + BN_EPS);
        float a = gamma[i] * inv_std;
        float d = beta[i] - mean * a;
        vfloat4* T = reinterpret_cast<vfloat4*>(ws + 4 * NROW);
        vfloat4 e;
        e.x = a; e.y = d; e.z = (float)(r * EE); e.w = (float)(c * EE);
        T[i] = e;
    }
}

// out[b,i,e1,e2] = ((xj[b,r,e1]*xi[b,c,e2]) * a[i] + d[i]) * W[e1,e2]
// Block: 256 threads = 4 waves; each wave handles 4 consecutive channels,
// block handles 16 channels for one batch b. Wave writes contiguous 1 KB
// per channel (64 lanes x float4), block writes contiguous 16 KB.
__global__ __launch_bounds__(256) void
cross_bn_kernel(const float* __restrict__ xi,
                const float* __restrict__ xj,
                const float* __restrict__ W,
                const float* __restrict__ ws,
                float* __restrict__ out) {
    const int NROW = BB * FF;
    const vfloat4* T = reinterpret_cast<const vfloat4*>(ws + 4 * NROW);

    int b = blockIdx.y;
    int t = threadIdx.x;
    int l = t & 63;        // lane in wave
    int e1 = l >> 2;       // 0..15
    int e2q = l & 3;       // float4 index along e2
    int wv = t >> 6;       // wave id 0..3

    vfloat4 w4 = reinterpret_cast<const vfloat4*>(W)[e1 * 4 + e2q];

    const float* xib = xi + b * FF * EE;
    const float* xjb = xj + b * FF * EE;
    float* outb = out + (size_t)b * II * EE * EE;

    int ibase = blockIdx.x * 16 + wv * 4;
#pragma unroll
    for (int k = 0; k < 4; ++k) {
        int i = ibase + k;
        if (i >= II) break;  // wave-uniform
        vfloat4 tb = T[i];   // (a, d, r*16, c*16) — broadcast load
        int joff = (int)tb.z;
        int coff = (int)tb.w;
        float xjs = xjb[joff + e1];
        vfloat4 xi4 = reinterpret_cast<const vfloat4*>(xib + coff)[e2q];
        vfloat4 o;
        o.x = (xjs * xi4.x * tb.x + tb.y) * w4.x;
        o.y = (xjs * xi4.y * tb.x + tb.y) * w4.y;
        o.z = (xjs * xi4.z * tb.x + tb.y) * w4.z;
        o.w = (xjs * xi4.w * tb.x + tb.y) * w4.w;
        vfloat4* dst = reinterpret_cast<vfloat4*>(outb + (size_t)i * (EE * EE)) + l;
        __builtin_nontemporal_store(o, dst);
    }
}

extern "C" void kernel_launch(void* const* d_in, const int* in_sizes, int n_in,
                              void* d_out, int out_size, void* d_ws, size_t ws_size,
                              hipStream_t stream) {
    const float* xi = (const float*)d_in[0];
    const float* xj = (const float*)d_in[1];
    const float* W = (const float*)d_in[2];
    const float* gamma = (const float*)d_in[3];
    const float* beta = (const float*)d_in[4];
    float* out = (float*)d_out;
    float* ws = (float*)d_ws;

    const int NROW = BB * FF;
    rowsum_kernel<<<dim3((2 * NROW + 255) / 256), 256, 0, stream>>>(xi, xj, ws);
    stats_kernel<<<dim3((II * 64 + 255) / 256), 256, 0, stream>>>(gamma, beta, ws);
    cross_bn_kernel<<<dim3((II + 15) / 16, BB), 256, 0, stream>>>(xi, xj, W, ws, out);
}

// Round 4
// 48.364 us; speedup vs baseline: 1.2625x; 1.0650x over previous
//
#include <hip/hip_runtime.h>
#include <math.h>

#define BB 256
#define FF 39
#define EE 16
#define II 741
#define BN_EPS 1e-5f

typedef float vfloat4 __attribute__((ext_vector_type(4)));

// ws layout (floats): T[I]*4 = (a, d, r*16, c*16) per channel. ~12 KB.

// One wave per channel. Lanes split the batch dim; each lane recomputes the
// per-row sums/sumsq it needs directly from xi/xj (L2-resident, ~32 KB/wave),
// butterfly-reduces, lane 0 folds BN stats into affine (a,d) + row offsets.
__global__ __launch_bounds__(256) void
stats_kernel(const float* __restrict__ xi,
             const float* __restrict__ xj,
             const float* __restrict__ gamma,
             const float* __restrict__ beta,
             float* __restrict__ ws) {
    int wid = (blockIdx.x * blockDim.x + threadIdx.x) >> 6;  // global wave = channel
    int lane = threadIdx.x & 63;
    if (wid >= II) return;
    int i = wid;
    // invert strict-lower-tri row-major index: i = r*(r-1)/2 + c, c < r
    int r = (int)((1.0f + sqrtf(8.0f * (float)i + 1.0f)) * 0.5f);
    while (r * (r - 1) / 2 > i) --r;
    while ((r + 1) * r / 2 <= i) ++r;
    int c = i - r * (r - 1) / 2;

    float sumS = 0.f, sumQ = 0.f;
#pragma unroll
    for (int b = lane; b < BB; b += 64) {
        const vfloat4* xjr = reinterpret_cast<const vfloat4*>(xj + (b * FF + r) * EE);
        const vfloat4* xic = reinterpret_cast<const vfloat4*>(xi + (b * FF + c) * EE);
        float sj = 0.f, qj = 0.f, si = 0.f, qi = 0.f;
#pragma unroll
        for (int k = 0; k < 4; ++k) {
            vfloat4 vj = xjr[k];
            vfloat4 vi = xic[k];
            sj += vj.x + vj.y + vj.z + vj.w;
            qj += vj.x * vj.x + vj.y * vj.y + vj.z * vj.z + vj.w * vj.w;
            si += vi.x + vi.y + vi.z + vi.w;
            qi += vi.x * vi.x + vi.y * vi.y + vi.z * vi.z + vi.w * vi.w;
        }
        sumS += sj * si;
        sumQ += qj * qi;
    }
#pragma unroll
    for (int off = 32; off > 0; off >>= 1) {
        sumS += __shfl_xor(sumS, off);
        sumQ += __shfl_xor(sumQ, off);
    }
    if (lane == 0) {
        const float invN = 1.0f / (float)(BB * EE * EE);  // 1/65536
        float mean = sumS * invN;
        float ex2 = sumQ * invN;
        float var = ex2 - mean * mean;
        float inv_std = 1.0f / sqrtf(var + BN_EPS);
        float a = gamma[i] * inv_std;
        float d = beta[i] - mean * a;
        vfloat4 e;
        e.x = a; e.y = d; e.z = (float)(r * EE); e.w = (float)(c * EE);
        reinterpret_cast<vfloat4*>(ws)[i] = e;
    }
}

// out[b,i,e1,e2] = ((xj[b,r,e1]*xi[b,c,e2]) * a[i] + d[i]) * W[e1,e2]
// Block: 256 threads = 4 waves; each wave handles 8 consecutive channels
// (block: 32 channels, 32 KB contiguous). Full tiles take a branchless path
// with all loads staged ahead of the 8 independent nt-store chains.
#define CPW 8  // channels per wave
__global__ __launch_bounds__(256) void
cross_bn_kernel(const float* __restrict__ xi,
                const float* __restrict__ xj,
                const float* __restrict__ W,
                const float* __restrict__ ws,
                float* __restrict__ out) {
    const vfloat4* T = reinterpret_cast<const vfloat4*>(ws);

    int b = blockIdx.y;
    int t = threadIdx.x;
    int l = t & 63;        // lane in wave
    int e1 = l >> 2;       // 0..15
    int e2q = l & 3;       // float4 index along e2
    int wv = t >> 6;       // wave id 0..3

    vfloat4 w4 = reinterpret_cast<const vfloat4*>(W)[e1 * 4 + e2q];

    const float* xib = xi + b * FF * EE;
    const float* xjb = xj + b * FF * EE;
    float* outb = out + (size_t)b * II * EE * EE;

    int ibase = blockIdx.x * (4 * CPW) + wv * CPW;

    if (ibase + CPW <= II) {
        // fast path: stage everything, then stream 8 stores
        vfloat4 tb[CPW];
#pragma unroll
        for (int k = 0; k < CPW; ++k) tb[k] = T[ibase + k];
        float xjs[CPW];
        vfloat4 xi4[CPW];
#pragma unroll
        for (int k = 0; k < CPW; ++k) {
            xjs[k] = xjb[(int)tb[k].z + e1];
            xi4[k] = reinterpret_cast<const vfloat4*>(xib + (int)tb[k].w)[e2q];
        }
#pragma unroll
        for (int k = 0; k < CPW; ++k) {
            vfloat4 o;
            o.x = (xjs[k] * xi4[k].x * tb[k].x + tb[k].y) * w4.x;
            o.y = (xjs[k] * xi4[k].y * tb[k].x + tb[k].y) * w4.y;
            o.z = (xjs[k] * xi4[k].z * tb[k].x + tb[k].y) * w4.z;
            o.w = (xjs[k] * xi4[k].w * tb[k].x + tb[k].y) * w4.w;
            vfloat4* dst = reinterpret_cast<vfloat4*>(outb + (size_t)(ibase + k) * (EE * EE)) + l;
            __builtin_nontemporal_store(o, dst);
        }
    } else {
        // tail path (last blockIdx.x only)
#pragma unroll
        for (int k = 0; k < CPW; ++k) {
            int i = ibase + k;
            if (i >= II) break;  // wave-uniform
            vfloat4 tb = T[i];
            float xjs = xjb[(int)tb.z + e1];
            vfloat4 xi4 = reinterpret_cast<const vfloat4*>(xib + (int)tb.w)[e2q];
            vfloat4 o;
            o.x = (xjs * xi4.x * tb.x + tb.y) * w4.x;
            o.y = (xjs * xi4.y * tb.x + tb.y) * w4.y;
            o.z = (xjs * xi4.z * tb.x + tb.y) * w4.z;
            o.w = (xjs * xi4.w * tb.x + tb.y) * w4.w;
            vfloat4* dst = reinterpret_cast<vfloat4*>(outb + (size_t)i * (EE * EE)) + l;
            __builtin_nontemporal_store(o, dst);
        }
    }
}

extern "C" void kernel_launch(void* const* d_in, const int* in_sizes, int n_in,
                              void* d_out, int out_size, void* d_ws, size_t ws_size,
                              hipStream_t stream) {
    const float* xi = (const float*)d_in[0];
    const float* xj = (const float*)d_in[1];
    const float* W = (const float*)d_in[2];
    const float* gamma = (const float*)d_in[3];
    const float* beta = (const float*)d_in[4];
    float* out = (float*)d_out;
    float* ws = (float*)d_ws;

    stats_kernel<<<dim3((II * 64 + 255) / 256), 256, 0, stream>>>(xi, xj, gamma, beta, ws);
    const int CPB = 4 * CPW;  // channels per block = 32
    cross_bn_kernel<<<dim3((II + CPB - 1) / CPB, BB), 256, 0, stream>>>(xi, xj, W, ws, out);
}

// Round 5
// 45.276 us; speedup vs baseline: 1.3486x; 1.0682x over previous
//
#include <hip/hip_runtime.h>
#include <math.h>

#define BB 256
#define FF 39
#define EE 16
#define II 741
#define BN_EPS 1e-5f

typedef float vfloat4 __attribute__((ext_vector_type(4)));

// ws layout (floats): T[I]*4 = (a, d, r*16, c*16) per channel. ~12 KB.

// One wave per channel. Lanes split the batch dim; each lane recomputes the
// per-row sums/sumsq it needs directly from xi/xj (L2-resident, ~32 KB/wave),
// butterfly-reduces, lane 0 folds BN stats into affine (a,d) + row offsets.
__global__ __launch_bounds__(256) void
stats_kernel(const float* __restrict__ xi,
             const float* __restrict__ xj,
             const float* __restrict__ gamma,
             const float* __restrict__ beta,
             float* __restrict__ ws) {
    int wid = (blockIdx.x * blockDim.x + threadIdx.x) >> 6;  // global wave = channel
    int lane = threadIdx.x & 63;
    if (wid >= II) return;
    int i = wid;
    // invert strict-lower-tri row-major index: i = r*(r-1)/2 + c, c < r
    int r = (int)((1.0f + sqrtf(8.0f * (float)i + 1.0f)) * 0.5f);
    while (r * (r - 1) / 2 > i) --r;
    while ((r + 1) * r / 2 <= i) ++r;
    int c = i - r * (r - 1) / 2;

    float sumS = 0.f, sumQ = 0.f;
#pragma unroll
    for (int b = lane; b < BB; b += 64) {
        const vfloat4* xjr = reinterpret_cast<const vfloat4*>(xj + (b * FF + r) * EE);
        const vfloat4* xic = reinterpret_cast<const vfloat4*>(xi + (b * FF + c) * EE);
        float sj = 0.f, qj = 0.f, si = 0.f, qi = 0.f;
#pragma unroll
        for (int k = 0; k < 4; ++k) {
            vfloat4 vj = xjr[k];
            vfloat4 vi = xic[k];
            sj += vj.x + vj.y + vj.z + vj.w;
            qj += vj.x * vj.x + vj.y * vj.y + vj.z * vj.z + vj.w * vj.w;
            si += vi.x + vi.y + vi.z + vi.w;
            qi += vi.x * vi.x + vi.y * vi.y + vi.z * vi.z + vi.w * vi.w;
        }
        sumS += sj * si;
        sumQ += qj * qi;
    }
#pragma unroll
    for (int off = 32; off > 0; off >>= 1) {
        sumS += __shfl_xor(sumS, off);
        sumQ += __shfl_xor(sumQ, off);
    }
    if (lane == 0) {
        const float invN = 1.0f / (float)(BB * EE * EE);  // 1/65536
        float mean = sumS * invN;
        float ex2 = sumQ * invN;
        float var = ex2 - mean * mean;
        float inv_std = 1.0f / sqrtf(var + BN_EPS);
        float a = gamma[i] * inv_std;
        float d = beta[i] - mean * a;
        vfloat4 e;
        e.x = a; e.y = d; e.z = (float)(r * EE); e.w = (float)(c * EE);
        reinterpret_cast<vfloat4*>(ws)[i] = e;
    }
}

// out[b,i,e1,e2] = ((xj[b,r,e1]*xi[b,c,e2]) * a[i] + d[i]) * W[e1,e2]
// Block: 256 threads = 4 waves; each wave handles 8 consecutive channels
// (block: 32 channels, 32 KB contiguous). Full tiles take a branchless path
// with all loads staged ahead of the 8 independent store chains.
// Plain (non-NT) stores: single-variable A/B vs round 4's nt stores.
#define CPW 8  // channels per wave
__global__ __launch_bounds__(256) void
cross_bn_kernel(const float* __restrict__ xi,
                const float* __restrict__ xj,
                const float* __restrict__ W,
                const float* __restrict__ ws,
                float* __restrict__ out) {
    const vfloat4* T = reinterpret_cast<const vfloat4*>(ws);

    int b = blockIdx.y;
    int t = threadIdx.x;
    int l = t & 63;        // lane in wave
    int e1 = l >> 2;       // 0..15
    int e2q = l & 3;       // float4 index along e2
    int wv = t >> 6;       // wave id 0..3

    vfloat4 w4 = reinterpret_cast<const vfloat4*>(W)[e1 * 4 + e2q];

    const float* xib = xi + b * FF * EE;
    const float* xjb = xj + b * FF * EE;
    float* outb = out + (size_t)b * II * EE * EE;

    int ibase = blockIdx.x * (4 * CPW) + wv * CPW;

    if (ibase + CPW <= II) {
        // fast path: stage everything, then stream 8 stores
        vfloat4 tb[CPW];
#pragma unroll
        for (int k = 0; k < CPW; ++k) tb[k] = T[ibase + k];
        float xjs[CPW];
        vfloat4 xi4[CPW];
#pragma unroll
        for (int k = 0; k < CPW; ++k) {
            xjs[k] = xjb[(int)tb[k].z + e1];
            xi4[k] = reinterpret_cast<const vfloat4*>(xib + (int)tb[k].w)[e2q];
        }
#pragma unroll
        for (int k = 0; k < CPW; ++k) {
            vfloat4 o;
            o.x = (xjs[k] * xi4[k].x * tb[k].x + tb[k].y) * w4.x;
            o.y = (xjs[k] * xi4[k].y * tb[k].x + tb[k].y) * w4.y;
            o.z = (xjs[k] * xi4[k].z * tb[k].x + tb[k].y) * w4.z;
            o.w = (xjs[k] * xi4[k].w * tb[k].x + tb[k].y) * w4.w;
            vfloat4* dst = reinterpret_cast<vfloat4*>(outb + (size_t)(ibase + k) * (EE * EE)) + l;
            *dst = o;
        }
    } else {
        // tail path (last blockIdx.x only)
#pragma unroll
        for (int k = 0; k < CPW; ++k) {
            int i = ibase + k;
            if (i >= II) break;  // wave-uniform
            vfloat4 tb = T[i];
            float xjs = xjb[(int)tb.z + e1];
            vfloat4 xi4 = reinterpret_cast<const vfloat4*>(xib + (int)tb.w)[e2q];
            vfloat4 o;
            o.x = (xjs * xi4.x * tb.x + tb.y) * w4.x;
            o.y = (xjs * xi4.y * tb.x + tb.y) * w4.y;
            o.z = (xjs * xi4.z * tb.x + tb.y) * w4.z;
            o.w = (xjs * xi4.w * tb.x + tb.y) * w4.w;
            vfloat4* dst = reinterpret_cast<vfloat4*>(outb + (size_t)i * (EE * EE)) + l;
            *dst = o;
        }
    }
}

extern "C" void kernel_launch(void* const* d_in, const int* in_sizes, int n_in,
                              void* d_out, int out_size, void* d_ws, size_t ws_size,
                              hipStream_t stream) {
    const float* xi = (const float*)d_in[0];
    const float* xj = (const float*)d_in[1];
    const float* W = (const float*)d_in[2];
    const float* gamma = (const float*)d_in[3];
    const float* beta = (const float*)d_in[4];
    float* out = (float*)d_out;
    float* ws = (float*)d_ws;

    stats_kernel<<<dim3((II * 64 + 255) / 256), 256, 0, stream>>>(xi, xj, gamma, beta, ws);
    const int CPB = 4 * CPW;  // channels per block = 32
    cross_bn_kernel<<<dim3((II + CPB - 1) / CPB, BB), 256, 0, stream>>>(xi, xj, W, ws, out);
}

// Round 6
// 43.142 us; speedup vs baseline: 1.4153x; 1.0495x over previous
//
#include <hip/hip_runtime.h>
#include <math.h>

#define BB 256
#define FF 39
#define EE 16
#define II 741
#define BN_EPS 1e-5f
#define CPW 8   // channels per wave
#define NB 4    // batches per block (main kernel)

typedef float vfloat4 __attribute__((ext_vector_type(4)));
typedef float vfloat2 __attribute__((ext_vector_type(2)));

// Compile-time strict-lower-triangle offsets: v[i] = (r*EE)<<16 | (c*EE),
// row-major pair order matching np.tril_indices(F, -1).
struct OffTab { unsigned int v[II]; };
static constexpr OffTab make_off() {
    OffTab t{};
    int i = 0;
    for (int r = 1; r < FF; ++r)
        for (int c = 0; c < r; ++c) {
            t.v[i] = ((unsigned)(r * EE) << 16) | (unsigned)(c * EE);
            ++i;
        }
    return t;
}
__constant__ OffTab g_off = make_off();

// ws layout (floats): T2[I] = (a, d) per channel. ~6 KB.

// One wave per channel. Lanes split the batch dim; each lane recomputes the
// per-row sums/sumsq it needs directly from xi/xj (L2-resident),
// butterfly-reduces, lane 0 folds BN stats into affine (a,d).
__global__ __launch_bounds__(256) void
stats_kernel(const float* __restrict__ xi,
             const float* __restrict__ xj,
             const float* __restrict__ gamma,
             const float* __restrict__ beta,
             float* __restrict__ ws) {
    int wid = (blockIdx.x * blockDim.x + threadIdx.x) >> 6;  // global wave = channel
    int lane = threadIdx.x & 63;
    if (wid >= II) return;
    int i = wid;
    unsigned o = g_off.v[i];
    int joff = (int)(o >> 16);
    int coff = (int)(o & 0xffffu);

    float sumS = 0.f, sumQ = 0.f;
#pragma unroll
    for (int b = lane; b < BB; b += 64) {
        const vfloat4* xjr = reinterpret_cast<const vfloat4*>(xj + b * FF * EE + joff);
        const vfloat4* xic = reinterpret_cast<const vfloat4*>(xi + b * FF * EE + coff);
        float sj = 0.f, qj = 0.f, si = 0.f, qi = 0.f;
#pragma unroll
        for (int k = 0; k < 4; ++k) {
            vfloat4 vj = xjr[k];
            vfloat4 vi = xic[k];
            sj += vj.x + vj.y + vj.z + vj.w;
            qj += vj.x * vj.x + vj.y * vj.y + vj.z * vj.z + vj.w * vj.w;
            si += vi.x + vi.y + vi.z + vi.w;
            qi += vi.x * vi.x + vi.y * vi.y + vi.z * vi.z + vi.w * vi.w;
        }
        sumS += sj * si;
        sumQ += qj * qi;
    }
#pragma unroll
    for (int off = 32; off > 0; off >>= 1) {
        sumS += __shfl_xor(sumS, off);
        sumQ += __shfl_xor(sumQ, off);
    }
    if (lane == 0) {
        const float invN = 1.0f / (float)(BB * EE * EE);  // 1/65536
        float mean = sumS * invN;
        float ex2 = sumQ * invN;
        float var = ex2 - mean * mean;
        float inv_std = 1.0f / sqrtf(var + BN_EPS);
        float a = gamma[i] * inv_std;
        float d = beta[i] - mean * a;
        vfloat2 e;
        e.x = a; e.y = d;
        reinterpret_cast<vfloat2*>(ws)[i] = e;
    }
}

// out[b,i,e1,e2] = ((xj[b,r,e1]*xi[b,c,e2]) * a[i] + d[i]) * W[e1,e2]
// Block: 256 threads = 4 waves; each wave owns 8 consecutive channels and
// NB=4 batches: per-channel scalars loaded once, then 4 rounds of
// (16 indep loads -> 8 contiguous-1KB stores). Loads for batch b+1 are
// independent of stores for b -> natural software pipeline.
__global__ __launch_bounds__(256) void
cross_bn_kernel(const float* __restrict__ xi,
                const float* __restrict__ xj,
                const float* __restrict__ W,
                const float* __restrict__ ws,
                float* __restrict__ out) {
    const vfloat2* T2 = reinterpret_cast<const vfloat2*>(ws);

    int t = threadIdx.x;
    int l = t & 63;        // lane in wave
    int e1 = l >> 2;       // 0..15
    int e2q = l & 3;       // float4 index along e2
    int wv = t >> 6;       // wave id 0..3

    vfloat4 w4 = reinterpret_cast<const vfloat4*>(W)[e1 * 4 + e2q];

    int ibase = __builtin_amdgcn_readfirstlane(blockIdx.x * (4 * CPW) + wv * CPW);
    int b0 = blockIdx.y * NB;

    if (ibase + CPW <= II) {
        // per-channel scalars (wave-uniform -> scalar loads)
        int joff[CPW], coff[CPW];
        float a[CPW], d[CPW];
#pragma unroll
        for (int k = 0; k < CPW; ++k) {
            unsigned o = g_off.v[ibase + k];
            joff[k] = (int)(o >> 16);
            coff[k] = (int)(o & 0xffffu);
            vfloat2 ad = T2[ibase + k];
            a[k] = ad.x; d[k] = ad.y;
        }
#pragma unroll
        for (int bb = 0; bb < NB; ++bb) {
            int b = b0 + bb;
            const float* xib = xi + b * FF * EE;
            const float* xjb = xj + b * FF * EE;
            float* outb = out + (size_t)b * (II * EE * EE) + (size_t)ibase * (EE * EE);
            float xjs[CPW];
            vfloat4 xi4[CPW];
#pragma unroll
            for (int k = 0; k < CPW; ++k) {
                xjs[k] = xjb[joff[k] + e1];
                xi4[k] = reinterpret_cast<const vfloat4*>(xib + coff[k])[e2q];
            }
#pragma unroll
            for (int k = 0; k < CPW; ++k) {
                vfloat4 o4;
                o4.x = (xjs[k] * xi4[k].x * a[k] + d[k]) * w4.x;
                o4.y = (xjs[k] * xi4[k].y * a[k] + d[k]) * w4.y;
                o4.z = (xjs[k] * xi4[k].z * a[k] + d[k]) * w4.z;
                o4.w = (xjs[k] * xi4[k].w * a[k] + d[k]) * w4.w;
                reinterpret_cast<vfloat4*>(outb + k * (EE * EE))[l] = o4;
            }
        }
    } else {
        // tail path (last blockIdx.x only; 741 = 23*32 + 5)
#pragma unroll
        for (int bb = 0; bb < NB; ++bb) {
            int b = b0 + bb;
            const float* xib = xi + b * FF * EE;
            const float* xjb = xj + b * FF * EE;
            float* outb = out + (size_t)b * (II * EE * EE);
            for (int k = 0; k < CPW; ++k) {
                int i = ibase + k;
                if (i >= II) break;  // wave-uniform
                unsigned o = g_off.v[i];
                int joff = (int)(o >> 16);
                int coff = (int)(o & 0xffffu);
                vfloat2 ad = T2[i];
                float xjs = xjb[joff + e1];
                vfloat4 xi4 = reinterpret_cast<const vfloat4*>(xib + coff)[e2q];
                vfloat4 o4;
                o4.x = (xjs * xi4.x * ad.x + ad.y) * w4.x;
                o4.y = (xjs * xi4.y * ad.x + ad.y) * w4.y;
                o4.z = (xjs * xi4.z * ad.x + ad.y) * w4.z;
                o4.w = (xjs * xi4.w * ad.x + ad.y) * w4.w;
                reinterpret_cast<vfloat4*>(outb + (size_t)i * (EE * EE))[l] = o4;
            }
        }
    }
}

extern "C" void kernel_launch(void* const* d_in, const int* in_sizes, int n_in,
                              void* d_out, int out_size, void* d_ws, size_t ws_size,
                              hipStream_t stream) {
    const float* xi = (const float*)d_in[0];
    const float* xj = (const float*)d_in[1];
    const float* W = (const float*)d_in[2];
    const float* gamma = (const float*)d_in[3];
    const float* beta = (const float*)d_in[4];
    float* out = (float*)d_out;
    float* ws = (float*)d_ws;

    stats_kernel<<<dim3((II * 64 + 255) / 256), 256, 0, stream>>>(xi, xj, gamma, beta, ws);
    const int CPB = 4 * CPW;  // channels per block = 32
    cross_bn_kernel<<<dim3((II + CPB - 1) / CPB, BB / NB), 256, 0, stream>>>(xi, xj, W, ws, out);
}